// Round 9
// baseline (260.828 us; speedup 1.0000x reference)
//
#include <hip/hip_runtime.h>

// RelGraphConv basis-decomposition forward, MI355X.
//
// Input-space reformulation:
//   g[d, b, :] = sum_{e: dst_e = d} w_comp[et_e, b] * feat[src_e, :]   (b = 0,1)
//   out[d]     = g[d,0] @ V0 + g[d,1] @ V1 + feat[d] @ W_loop + bias
//
// Pipeline:
//   k_cvt (feat -> bf16, RNE) ; memset bcnt -> k_bhist -> k_bscan ->
//   k_bscatter (coarse 391-bucket multisplit) -> k_fine (per-bucket exact
//   per-node CSR in LDS) -> k_gather_post (FUSED: bf16 gather, 4 edges per
//   dwordx2 load, then in-block dense [g0,g1,feat](192)->64 GEMM).
//
// NOTE: __launch_bounds__(256, 4) — round 8 used (256, 8), which capped the
// allocator at 32 VGPRs and spilled everything (WRITE_SIZE 25->222 MB).

constexpr int N_NODES  = 100000;
constexpr int N_EDGES  = 1600000;
constexpr int IN_FEAT  = 64;
constexpr int OUT_FEAT = 64;

constexpr int BN = 256;                                // nodes per bucket
constexpr int NB = (N_NODES + BN - 1) / BN;            // 391 buckets
constexpr int SC_CHUNK = 4096;                         // edges per scatter block

constexpr int NODES_PER_GRP = 8;
constexpr int N_GRP  = N_NODES / NODES_PER_GRP;        // 12500 (exact)
constexpr int GP_GRID = 2500;                          // 5 groups per block, exact

// entry pack: dst_low(8) | src(17) | etype(6)
__device__ __forceinline__ unsigned pack_entry(int d, int s, int r) {
    return (unsigned)(d & (BN - 1)) | ((unsigned)s << 8) | ((unsigned)r << 25);
}

__device__ __forceinline__ unsigned bf16_rne(float f) {
    unsigned b = __float_as_uint(f);
    b += 0x7fffu + ((b >> 16) & 1u);
    return b >> 16;
}

// ---------------------------------------------------------------- f32->bf16
__global__ __launch_bounds__(256) void k_cvt(const float* __restrict__ feat,
                                             unsigned* __restrict__ fbf) {
    const int total = N_NODES * 16;    // float4 count
    const float4* __restrict__ f4 = (const float4*)feat;
    uint2* __restrict__ o2 = (uint2*)fbf;
    for (int i = blockIdx.x * 256 + threadIdx.x; i < total; i += gridDim.x * 256) {
        const float4 f = f4[i];
        uint2 o;
        o.x = bf16_rne(f.x) | (bf16_rne(f.y) << 16);
        o.y = bf16_rne(f.z) | (bf16_rne(f.w) << 16);
        o2[i] = o;
    }
}

// ---------------------------------------------------------------- coarse hist
__global__ __launch_bounds__(256) void k_bhist(const int* __restrict__ dst,
                                               int* __restrict__ bcnt) {
    __shared__ int hist[NB];
    const int t = threadIdx.x;
    for (int i = t; i < NB; i += 256) hist[i] = 0;
    __syncthreads();
    const int cbase = blockIdx.x * 2048;
    #pragma unroll
    for (int k = 0; k < 8; ++k) {
        const int e = cbase + k * 256 + t;
        if (e < N_EDGES) atomicAdd(&hist[dst[e] >> 8], 1);
    }
    __syncthreads();
    for (int i = t; i < NB; i += 256)
        if (hist[i]) atomicAdd(&bcnt[i], hist[i]);
}

// ---------------------------------------------------------------- coarse scan
__global__ __launch_bounds__(512) void k_bscan(const int* __restrict__ bcnt,
                                               int* __restrict__ bbase,
                                               int* __restrict__ bcursor) {
    __shared__ int part[512];
    const int t = threadIdx.x;
    const int v = (t < NB) ? bcnt[t] : 0;
    part[t] = v;
    __syncthreads();
    for (int d = 1; d < 512; d <<= 1) {
        const int u = (t >= d) ? part[t - d] : 0;
        __syncthreads();
        part[t] += u;
        __syncthreads();
    }
    if (t < NB) {
        const int ex = part[t] - v;   // exclusive
        bbase[t] = ex;
        bcursor[t] = ex;
    }
    if (t == 0) bbase[NB] = N_EDGES;
}

// ---------------------------------------------------------------- multisplit
__global__ __launch_bounds__(256) void k_bscatter(const int* __restrict__ src,
                                                  const int* __restrict__ dst,
                                                  const int* __restrict__ et,
                                                  int* __restrict__ bcursor,
                                                  unsigned* __restrict__ sorted_c) {
    __shared__ int hist[NB], gb[NB], lcur[NB];
    const int t = threadIdx.x;
    const int cbase = blockIdx.x * SC_CHUNK;
    for (int i = t; i < NB; i += 256) { hist[i] = 0; lcur[i] = 0; }
    __syncthreads();
    #pragma unroll 1
    for (int k = 0; k < SC_CHUNK / 256; ++k) {
        const int e = cbase + k * 256 + t;
        if (e < N_EDGES) atomicAdd(&hist[dst[e] >> 8], 1);
    }
    __syncthreads();
    for (int i = t; i < NB; i += 256) {
        const int c = hist[i];
        gb[i] = c ? atomicAdd(&bcursor[i], c) : 0;
    }
    __syncthreads();
    #pragma unroll 1
    for (int k = 0; k < SC_CHUNK / 256; ++k) {
        const int e = cbase + k * 256 + t;
        if (e < N_EDGES) {
            const int d = dst[e];
            const int bkt = d >> 8;
            const int r = atomicAdd(&lcur[bkt], 1);
            sorted_c[gb[bkt] + r] = pack_entry(d, src[e], et[e]);
        }
    }
}

// ---------------------------------------------------------------- fine CSR
__global__ __launch_bounds__(256) void k_fine(const unsigned* __restrict__ sorted_c,
                                              const int* __restrict__ bbase,
                                              int* __restrict__ offsets,
                                              unsigned* __restrict__ sorted_f) {
    __shared__ int cnt[BN];
    __shared__ int part[BN];
    __shared__ int cur[BN];
    const int t = threadIdx.x;
    const int b = blockIdx.x;
    cnt[t] = 0;
    __syncthreads();
    const int base = bbase[b];
    const int end  = bbase[b + 1];
    for (int k = base + t; k < end; k += 256)
        atomicAdd(&cnt[sorted_c[k] & (BN - 1)], 1);
    __syncthreads();
    const int v = cnt[t];
    part[t] = v;
    __syncthreads();
    for (int d = 1; d < BN; d <<= 1) {
        const int u = (t >= d) ? part[t - d] : 0;
        __syncthreads();
        part[t] += u;
        __syncthreads();
    }
    const int node = b * BN + t;
    const int off = base + part[t] - v;   // exclusive within bucket
    if (node < N_NODES) offsets[node] = off;
    cur[t] = off;
    if (b == NB - 1 && t == 0) offsets[N_NODES] = N_EDGES;
    __syncthreads();
    for (int k = base + t; k < end; k += 256) {
        const unsigned en = sorted_c[k];
        const int pos = atomicAdd(&cur[en & (BN - 1)], 1);
        sorted_f[pos] = en;
    }
}

// ---------------------------------------------------------------- fused
// 256 threads = 4 waves; 2500 blocks x exactly 5 groups of 8 nodes.
// Phase 1: wave w gathers nodes grp*8+w and grp*8+4+w from bf16 feat.
//   Lane split: quarter q = lane>>4 picks edge slot, sl = lane&15 picks 4
//   cols (uint2 = 4 bf16). One dwordx2 load covers 4 edges across the wave.
//   Cross-quarter shfl_xor(16/32) reduce; lanes<16 write g to LDS.
// Phase 2: thread (seg=w, col=lane), 4 sub-chunks of 12 Wcat rows (bounded
//   VGPR), 8 node-partials in regs; LDS partial reduce; coalesced out.
__global__ __launch_bounds__(256, 4) void k_gather_post(
    const int*      __restrict__ offsets,
    const unsigned* __restrict__ sorted_f,
    const float*    __restrict__ w_comp,      // (64, 2)
    const float*    __restrict__ feat,        // (N, 64) f32
    const unsigned* __restrict__ fbf,         // (N, 64) bf16 packed as u32 x16
    const float*    __restrict__ weight,      // (2, 64, 64) -> Wcat rows 0..127
    const float*    __restrict__ loop_weight, // (64, 64)    -> Wcat rows 128..191
    const float*    __restrict__ h_bias,      // (64,)
    float*          __restrict__ out)         // (N, 64)
{
    __shared__ float4 Lin4[NODES_PER_GRP][48];  // [node][192 f32]: g0|g1|feat
    __shared__ float  ps[4][NODES_PER_GRP][64]; // [seg][node][col]
    __shared__ float2 wcl[64];                  // w_comp copy
    float* Lin = (float*)Lin4;

    const int tid  = threadIdx.x;
    const int lane = tid & 63;                // = col in phase 2
    const int w    = tid >> 6;                // wave = K-seg in phase 2
    const int q    = lane >> 4;               // edge slot within 4-group
    const int sl   = lane & 15;               // uint2 column within row

    if (tid < 64) wcl[tid] = ((const float2*)w_comp)[tid];
    const float bias = h_bias[lane];
    const uint2* __restrict__ fb2 = (const uint2*)fbf;  // row = 16 uint2

    #pragma unroll 1
    for (int g = 0; g < N_GRP / GP_GRID; ++g) {
        const int grp = blockIdx.x + g * GP_GRID;

        __syncthreads();   // prior ps reads done; Lin free; wcl visible (g=0)

        // ---- Phase 1: gather 2 nodes per wave ----
        #pragma unroll 1
        for (int half = 0; half < 2; ++half) {
            const int n = __builtin_amdgcn_readfirstlane(grp * 8 + half * 4 + w);
            const int start = __builtin_amdgcn_readfirstlane(offsets[n]);
            const int end   = __builtin_amdgcn_readfirstlane(offsets[n + 1]);
            const float fv = feat[(size_t)n * 64 + lane];

            float a0 = 0.f, a1 = 0.f, a2 = 0.f, a3 = 0.f;
            float b0 = 0.f, b1 = 0.f, b2 = 0.f, b3 = 0.f;
            int k = start;
            for (; k + 15 < end; k += 16) {
                unsigned pe[16];
                #pragma unroll
                for (int i = 0; i < 16; ++i) pe[i] = sorted_f[k + i];  // uniform -> s_load
                #pragma unroll
                for (int gi = 0; gi < 4; ++gi) {
                    unsigned p = pe[gi * 4];
                    p = (q == 1) ? pe[gi * 4 + 1] : p;
                    p = (q == 2) ? pe[gi * 4 + 2] : p;
                    p = (q == 3) ? pe[gi * 4 + 3] : p;
                    const int s = (p >> 8) & 0x1FFFF;
                    const uint2 d = fb2[(size_t)s * 16 + sl];
                    const float2 c = wcl[p >> 25];
                    const float f0 = __uint_as_float(d.x << 16);
                    const float f1 = __uint_as_float(d.x & 0xffff0000u);
                    const float f2 = __uint_as_float(d.y << 16);
                    const float f3 = __uint_as_float(d.y & 0xffff0000u);
                    a0 = fmaf(c.x, f0, a0); a1 = fmaf(c.x, f1, a1);
                    a2 = fmaf(c.x, f2, a2); a3 = fmaf(c.x, f3, a3);
                    b0 = fmaf(c.y, f0, b0); b1 = fmaf(c.y, f1, b1);
                    b2 = fmaf(c.y, f2, b2); b3 = fmaf(c.y, f3, b3);
                }
            }
            for (; k < end; k += 4) {                 // clamped 4-group tail
                const int rem = end - k;
                const int idx = k + ((q < rem) ? q : rem - 1);
                const unsigned p = sorted_f[idx];
                const int s = (p >> 8) & 0x1FFFF;
                const uint2 d = fb2[(size_t)s * 16 + sl];
                const float2 c = wcl[p >> 25];
                if (q < rem) {
                    const float f0 = __uint_as_float(d.x << 16);
                    const float f1 = __uint_as_float(d.x & 0xffff0000u);
                    const float f2 = __uint_as_float(d.y << 16);
                    const float f3 = __uint_as_float(d.y & 0xffff0000u);
                    a0 = fmaf(c.x, f0, a0); a1 = fmaf(c.x, f1, a1);
                    a2 = fmaf(c.x, f2, a2); a3 = fmaf(c.x, f3, a3);
                    b0 = fmaf(c.y, f0, b0); b1 = fmaf(c.y, f1, b1);
                    b2 = fmaf(c.y, f2, b2); b3 = fmaf(c.y, f3, b3);
                }
            }
            // reduce across the 4 quarters (lanes l, l^16, l^32, l^48)
            a0 += __shfl_xor(a0, 16); a0 += __shfl_xor(a0, 32);
            a1 += __shfl_xor(a1, 16); a1 += __shfl_xor(a1, 32);
            a2 += __shfl_xor(a2, 16); a2 += __shfl_xor(a2, 32);
            a3 += __shfl_xor(a3, 16); a3 += __shfl_xor(a3, 32);
            b0 += __shfl_xor(b0, 16); b0 += __shfl_xor(b0, 32);
            b1 += __shfl_xor(b1, 16); b1 += __shfl_xor(b1, 32);
            b2 += __shfl_xor(b2, 16); b2 += __shfl_xor(b2, 32);
            b3 += __shfl_xor(b3, 16); b3 += __shfl_xor(b3, 32);

            const int slot = half * 4 + w;
            if (lane < 16) {
                Lin4[slot][sl]      = make_float4(a0, a1, a2, a3);  // g0 cols 4sl..
                Lin4[slot][16 + sl] = make_float4(b0, b1, b2, b3);  // g1
            }
            Lin[slot * 192 + 128 + lane] = fv;                      // feat (f32)
        }
        __syncthreads();

        // ---- Phase 2: K-segment GEMM, 4 sub-chunks of 12 rows ----
        float pacc[8];
        #pragma unroll
        for (int j = 0; j < 8; ++j) pacc[j] = 0.0f;
        #pragma unroll 1
        for (int sub = 0; sub < 4; ++sub) {
            const int r0 = w * 48 + sub * 12;
            float wv[12];
            #pragma unroll
            for (int i = 0; i < 12; ++i) {
                const int r = r0 + i;
                wv[i] = (r < 128) ? weight[r * 64 + lane]
                                  : loop_weight[(r - 128) * 64 + lane];
            }
            #pragma unroll
            for (int j = 0; j < 8; ++j) {
                const float4* v4 = &Lin4[j][w * 12 + sub * 3];
                const float4 x = v4[0], y = v4[1], z = v4[2];
                float p0 = fmaf(x.x, wv[0], pacc[j]);
                p0 = fmaf(x.y, wv[1], p0);
                p0 = fmaf(x.z, wv[2], p0);
                p0 = fmaf(x.w, wv[3], p0);
                p0 = fmaf(y.x, wv[4], p0);
                p0 = fmaf(y.y, wv[5], p0);
                p0 = fmaf(y.z, wv[6], p0);
                p0 = fmaf(y.w, wv[7], p0);
                p0 = fmaf(z.x, wv[8], p0);
                p0 = fmaf(z.y, wv[9], p0);
                p0 = fmaf(z.z, wv[10], p0);
                p0 = fmaf(z.w, wv[11], p0);
                pacc[j] = p0;
            }
        }
        #pragma unroll
        for (int j = 0; j < 8; ++j) ps[w][j][lane] = pacc[j];
        __syncthreads();

        // Two outputs per thread: node slots w and w+4. Coalesced.
        #pragma unroll
        for (int half = 0; half < 2; ++half) {
            const int slot = half * 4 + w;
            out[(size_t)(grp * 8 + slot) * 64 + lane] =
                ps[0][slot][lane] + ps[1][slot][lane] +
                ps[2][slot][lane] + ps[3][slot][lane] + bias;
        }
    }
}

// ---------------------------------------------------------------- launch
extern "C" void kernel_launch(void* const* d_in, const int* in_sizes, int n_in,
                              void* d_out, int out_size, void* d_ws, size_t ws_size,
                              hipStream_t stream) {
    const float* feat        = (const float*)d_in[0];
    const float* weight      = (const float*)d_in[1];
    const float* w_comp      = (const float*)d_in[2];
    const float* loop_weight = (const float*)d_in[3];
    const float* h_bias      = (const float*)d_in[4];
    const int*   src         = (const int*)d_in[5];
    const int*   dst         = (const int*)d_in[6];
    const int*   etypes      = (const int*)d_in[7];
    float* out = (float*)d_out;

    // ws layout (4B units), ~26 MB total, no aliasing:
    unsigned* sorted_c = (unsigned*)d_ws;                     // 1.6M u32
    unsigned* sorted_f = sorted_c + N_EDGES;                  // 1.6M u32
    unsigned* fbf      = sorted_f + N_EDGES;                  // 3.2M u32 (bf16 feat)
    int*      offsets  = (int*)(fbf + N_NODES * 32);          // N+1
    int*      bcnt     = offsets + (N_NODES + 1);             // NB
    int*      bbase    = bcnt + NB;                           // NB+1
    int*      bcursor  = bbase + NB + 1;                      // NB

    k_cvt<<<2048, 256, 0, stream>>>(feat, fbf);
    hipMemsetAsync(bcnt, 0, NB * sizeof(int), stream);
    k_bhist<<<(N_EDGES + 2047) / 2048, 256, 0, stream>>>(dst, bcnt);
    k_bscan<<<1, 512, 0, stream>>>(bcnt, bbase, bcursor);
    k_bscatter<<<(N_EDGES + SC_CHUNK - 1) / SC_CHUNK, 256, 0, stream>>>(
        src, dst, etypes, bcursor, sorted_c);
    k_fine<<<NB, BN, 0, stream>>>(sorted_c, bbase, offsets, sorted_f);
    k_gather_post<<<GP_GRID, 256, 0, stream>>>(offsets, sorted_f, w_comp, feat,
                                               fbf, weight, loop_weight, h_bias, out);
}

// Round 10
// 165.590 us; speedup vs baseline: 1.5751x; 1.5751x over previous
//
#include <hip/hip_runtime.h>

// RelGraphConv basis-decomposition forward, MI355X.
//
// Input-space reformulation:
//   g[d, b, :] = sum_{e: dst_e = d} w_comp[et_e, b] * feat[src_e, :]   (b = 0,1)
//   out[d]     = g[d,0] @ V0 + g[d,1] @ V1 + feat[d] @ W_loop + bias
//
// Pipeline:
//   k_cvt (feat -> bf16) ; memset bcnt -> k_bhist -> k_bscan -> k_bscatter
//   (coarse 391-bucket multisplit) -> k_fine (per-bucket exact per-node CSR)
//   -> k_gather_post (FUSED: round-7 gather structure, but ushort bf16 loads
//      = 128 B/edge, then in-block dense [g0,g1,feat](192)->64 GEMM).
//
// History: r7 = this structure with f32 gather (110 us gather, VGPR 44, no
// spill). r8/r9 restructured loads and spilled (WRITE_SIZE 25->222/173 MB).
// This round: r7 verbatim + bf16 gather only.

constexpr int N_NODES  = 100000;
constexpr int N_EDGES  = 1600000;
constexpr int IN_FEAT  = 64;
constexpr int OUT_FEAT = 64;

constexpr int BN = 256;                                // nodes per bucket
constexpr int NB = (N_NODES + BN - 1) / BN;            // 391 buckets
constexpr int SC_CHUNK = 4096;                         // edges per scatter block

constexpr int NODES_PER_GRP = 8;
constexpr int N_GRP  = N_NODES / NODES_PER_GRP;        // 12500 (exact)
constexpr int GP_GRID = 2500;                          // 5 groups per block, exact

// entry pack: dst_low(8) | src(17) | etype(6)
__device__ __forceinline__ unsigned pack_entry(int d, int s, int r) {
    return (unsigned)(d & (BN - 1)) | ((unsigned)s << 8) | ((unsigned)r << 25);
}

__device__ __forceinline__ unsigned bf16_rne(float f) {
    unsigned b = __float_as_uint(f);
    b += 0x7fffu + ((b >> 16) & 1u);
    return b >> 16;
}

// ---------------------------------------------------------------- f32->bf16
__global__ __launch_bounds__(256) void k_cvt(const float* __restrict__ feat,
                                             unsigned* __restrict__ fbf) {
    const int total = N_NODES * 16;    // float4 count
    const float4* __restrict__ f4 = (const float4*)feat;
    uint2* __restrict__ o2 = (uint2*)fbf;
    for (int i = blockIdx.x * 256 + threadIdx.x; i < total; i += gridDim.x * 256) {
        const float4 f = f4[i];
        uint2 o;
        o.x = bf16_rne(f.x) | (bf16_rne(f.y) << 16);
        o.y = bf16_rne(f.z) | (bf16_rne(f.w) << 16);
        o2[i] = o;
    }
}

// ---------------------------------------------------------------- coarse hist
__global__ __launch_bounds__(256) void k_bhist(const int* __restrict__ dst,
                                               int* __restrict__ bcnt) {
    __shared__ int hist[NB];
    const int t = threadIdx.x;
    for (int i = t; i < NB; i += 256) hist[i] = 0;
    __syncthreads();
    const int cbase = blockIdx.x * 2048;
    #pragma unroll
    for (int k = 0; k < 8; ++k) {
        const int e = cbase + k * 256 + t;
        if (e < N_EDGES) atomicAdd(&hist[dst[e] >> 8], 1);
    }
    __syncthreads();
    for (int i = t; i < NB; i += 256)
        if (hist[i]) atomicAdd(&bcnt[i], hist[i]);
}

// ---------------------------------------------------------------- coarse scan
__global__ __launch_bounds__(512) void k_bscan(const int* __restrict__ bcnt,
                                               int* __restrict__ bbase,
                                               int* __restrict__ bcursor) {
    __shared__ int part[512];
    const int t = threadIdx.x;
    const int v = (t < NB) ? bcnt[t] : 0;
    part[t] = v;
    __syncthreads();
    for (int d = 1; d < 512; d <<= 1) {
        const int u = (t >= d) ? part[t - d] : 0;
        __syncthreads();
        part[t] += u;
        __syncthreads();
    }
    if (t < NB) {
        const int ex = part[t] - v;   // exclusive
        bbase[t] = ex;
        bcursor[t] = ex;
    }
    if (t == 0) bbase[NB] = N_EDGES;
}

// ---------------------------------------------------------------- multisplit
__global__ __launch_bounds__(256) void k_bscatter(const int* __restrict__ src,
                                                  const int* __restrict__ dst,
                                                  const int* __restrict__ et,
                                                  int* __restrict__ bcursor,
                                                  unsigned* __restrict__ sorted_c) {
    __shared__ int hist[NB], gb[NB], lcur[NB];
    const int t = threadIdx.x;
    const int cbase = blockIdx.x * SC_CHUNK;
    for (int i = t; i < NB; i += 256) { hist[i] = 0; lcur[i] = 0; }
    __syncthreads();
    #pragma unroll 1
    for (int k = 0; k < SC_CHUNK / 256; ++k) {
        const int e = cbase + k * 256 + t;
        if (e < N_EDGES) atomicAdd(&hist[dst[e] >> 8], 1);
    }
    __syncthreads();
    for (int i = t; i < NB; i += 256) {
        const int c = hist[i];
        gb[i] = c ? atomicAdd(&bcursor[i], c) : 0;
    }
    __syncthreads();
    #pragma unroll 1
    for (int k = 0; k < SC_CHUNK / 256; ++k) {
        const int e = cbase + k * 256 + t;
        if (e < N_EDGES) {
            const int d = dst[e];
            const int bkt = d >> 8;
            const int r = atomicAdd(&lcur[bkt], 1);
            sorted_c[gb[bkt] + r] = pack_entry(d, src[e], et[e]);
        }
    }
}

// ---------------------------------------------------------------- fine CSR
__global__ __launch_bounds__(256) void k_fine(const unsigned* __restrict__ sorted_c,
                                              const int* __restrict__ bbase,
                                              int* __restrict__ offsets,
                                              unsigned* __restrict__ sorted_f) {
    __shared__ int cnt[BN];
    __shared__ int part[BN];
    __shared__ int cur[BN];
    const int t = threadIdx.x;
    const int b = blockIdx.x;
    cnt[t] = 0;
    __syncthreads();
    const int base = bbase[b];
    const int end  = bbase[b + 1];
    for (int k = base + t; k < end; k += 256)
        atomicAdd(&cnt[sorted_c[k] & (BN - 1)], 1);
    __syncthreads();
    const int v = cnt[t];
    part[t] = v;
    __syncthreads();
    for (int d = 1; d < BN; d <<= 1) {
        const int u = (t >= d) ? part[t - d] : 0;
        __syncthreads();
        part[t] += u;
        __syncthreads();
    }
    const int node = b * BN + t;
    const int off = base + part[t] - v;   // exclusive within bucket
    if (node < N_NODES) offsets[node] = off;
    cur[t] = off;
    if (b == NB - 1 && t == 0) offsets[N_NODES] = N_EDGES;
    __syncthreads();
    for (int k = base + t; k < end; k += 256) {
        const unsigned en = sorted_c[k];
        const int pos = atomicAdd(&cur[en & (BN - 1)], 1);
        sorted_f[pos] = en;
    }
}

// ---------------------------------------------------------------- fused
// 256 threads = 4 waves; 2500 blocks x exactly 5 groups of 8 nodes.
// Phase 1: wave w register-gathers nodes grp*8+w and grp*8+4+w (8-deep
//          unroll -> 8 bf16 row loads in flight, 128 B/edge) -> LDS.
// Phase 2: thread (seg=w, col=lane) does the 48-row K-segment of the
//          192->64 GEMM for all 8 nodes; LDS partial reduce; coalesced out.
__global__ __launch_bounds__(256, 4) void k_gather_post(
    const int*      __restrict__ offsets,
    const unsigned* __restrict__ sorted_f,
    const float*    __restrict__ w_comp,      // (64, 2)
    const float*    __restrict__ feat,        // (N, 64) f32 (self-loop row)
    const unsigned short* __restrict__ fbs,   // (N, 64) bf16
    const float*    __restrict__ weight,      // (2, 64, 64)
    const float*    __restrict__ loop_weight, // (64, 64)
    const float*    __restrict__ h_bias,      // (64,)
    float*          __restrict__ out)         // (N, 64)
{
    __shared__ float4 Lin4[NODES_PER_GRP][48];  // [node][192 f32]: g0|g1|feat
    __shared__ float  ps[4][NODES_PER_GRP][64]; // [seg][node][col]
    float* Lin = (float*)Lin4;

    const int tid  = threadIdx.x;
    const int lane = tid & 63;                // = col in phase 2
    const int w    = tid >> 6;                // wave = K-seg in phase 2

    // Wcat (= [V0; V1; W_loop]) column segment, rows w*48..w*48+47.
    float wcol[48];
    #pragma unroll
    for (int i = 0; i < 48; ++i) {
        const int r = w * 48 + i;
        wcol[i] = (r < 64)  ? weight[r * 64 + lane]
                : (r < 128) ? weight[64 * 64 + (r - 64) * 64 + lane]
                            : loop_weight[(r - 128) * 64 + lane];
    }
    const float bias = h_bias[lane];
    const float2* __restrict__ wc = (const float2*)w_comp;

    #pragma unroll 1
    for (int g = 0; g < N_GRP / GP_GRID; ++g) {
        const int grp = blockIdx.x + g * GP_GRID;

        __syncthreads();   // prior iteration's ps reads complete; Lin free

        // ---- Phase 1: gather 2 nodes per wave ----
        #pragma unroll 1
        for (int half = 0; half < 2; ++half) {
            const int n = __builtin_amdgcn_readfirstlane(grp * 8 + half * 4 + w);
            const int start = __builtin_amdgcn_readfirstlane(offsets[n]);
            const int end   = __builtin_amdgcn_readfirstlane(offsets[n + 1]);
            const float fv = feat[(size_t)n * 64 + lane];

            float a0 = 0.f, b0 = 0.f, a1 = 0.f, b1 = 0.f;
            int k = start;
            for (; k + 7 < end; k += 8) {
                unsigned p[8]; float f[8];
                #pragma unroll
                for (int i = 0; i < 8; ++i) p[i] = sorted_f[k + i];   // uniform -> s_load
                #pragma unroll
                for (int i = 0; i < 8; ++i)
                    f[i] = __uint_as_float(
                        (unsigned)fbs[(size_t)((p[i] >> 8) & 0x1FFFF) * 64 + lane] << 16);
                #pragma unroll
                for (int i = 0; i < 8; ++i) {
                    const float2 c = wc[p[i] >> 25];
                    if (i & 1) { a1 = fmaf(c.x, f[i], a1); b1 = fmaf(c.y, f[i], b1); }
                    else       { a0 = fmaf(c.x, f[i], a0); b0 = fmaf(c.y, f[i], b0); }
                }
            }
            for (; k + 3 < end; k += 4) {
                unsigned p[4]; float f[4];
                #pragma unroll
                for (int i = 0; i < 4; ++i) p[i] = sorted_f[k + i];
                #pragma unroll
                for (int i = 0; i < 4; ++i)
                    f[i] = __uint_as_float(
                        (unsigned)fbs[(size_t)((p[i] >> 8) & 0x1FFFF) * 64 + lane] << 16);
                #pragma unroll
                for (int i = 0; i < 4; ++i) {
                    const float2 c = wc[p[i] >> 25];
                    if (i & 1) { a1 = fmaf(c.x, f[i], a1); b1 = fmaf(c.y, f[i], b1); }
                    else       { a0 = fmaf(c.x, f[i], a0); b0 = fmaf(c.y, f[i], b0); }
                }
            }
            for (; k < end; ++k) {
                const unsigned p0 = sorted_f[k];
                const float f0 = __uint_as_float(
                    (unsigned)fbs[(size_t)((p0 >> 8) & 0x1FFFF) * 64 + lane] << 16);
                const float2 c0 = wc[p0 >> 25];
                a0 = fmaf(c0.x, f0, a0); b0 = fmaf(c0.y, f0, b0);
            }
            const int slot = half * 4 + w;
            Lin[slot * 192 + lane]       = a0 + a1;
            Lin[slot * 192 + 64 + lane]  = b0 + b1;
            Lin[slot * 192 + 128 + lane] = fv;
        }
        __syncthreads();

        // ---- Phase 2: K-segment GEMM over 8 nodes ----
        #pragma unroll
        for (int j = 0; j < NODES_PER_GRP; ++j) {
            const float4* v4 = (const float4*)&Lin4[0][0] + j * 48 + w * 12;
            float p0 = 0.f, p1 = 0.f;
            #pragma unroll
            for (int i4 = 0; i4 < 12; i4 += 2) {
                const float4 x = v4[i4];       // uniform -> LDS broadcast
                const float4 y = v4[i4 + 1];
                p0 = fmaf(x.x, wcol[4 * i4 + 0], p0);
                p0 = fmaf(x.y, wcol[4 * i4 + 1], p0);
                p0 = fmaf(x.z, wcol[4 * i4 + 2], p0);
                p0 = fmaf(x.w, wcol[4 * i4 + 3], p0);
                p1 = fmaf(y.x, wcol[4 * i4 + 4], p1);
                p1 = fmaf(y.y, wcol[4 * i4 + 5], p1);
                p1 = fmaf(y.z, wcol[4 * i4 + 6], p1);
                p1 = fmaf(y.w, wcol[4 * i4 + 7], p1);
            }
            ps[w][j][lane] = p0 + p1;
        }
        __syncthreads();

        // Two outputs per thread: node slots w and w+4. Coalesced.
        #pragma unroll
        for (int half = 0; half < 2; ++half) {
            const int slot = half * 4 + w;
            out[(size_t)(grp * 8 + slot) * 64 + lane] =
                ps[0][slot][lane] + ps[1][slot][lane] +
                ps[2][slot][lane] + ps[3][slot][lane] + bias;
        }
    }
}

// ---------------------------------------------------------------- launch
extern "C" void kernel_launch(void* const* d_in, const int* in_sizes, int n_in,
                              void* d_out, int out_size, void* d_ws, size_t ws_size,
                              hipStream_t stream) {
    const float* feat        = (const float*)d_in[0];
    const float* weight      = (const float*)d_in[1];
    const float* w_comp      = (const float*)d_in[2];
    const float* loop_weight = (const float*)d_in[3];
    const float* h_bias      = (const float*)d_in[4];
    const int*   src         = (const int*)d_in[5];
    const int*   dst         = (const int*)d_in[6];
    const int*   etypes      = (const int*)d_in[7];
    float* out = (float*)d_out;

    // ws layout (4B units), ~26 MB total, no aliasing:
    unsigned* sorted_c = (unsigned*)d_ws;                     // 1.6M u32
    unsigned* sorted_f = sorted_c + N_EDGES;                  // 1.6M u32
    unsigned* fbf      = sorted_f + N_EDGES;                  // 3.2M u32 (bf16 feat)
    int*      offsets  = (int*)(fbf + N_NODES * 32);          // N+1
    int*      bcnt     = offsets + (N_NODES + 1);             // NB
    int*      bbase    = bcnt + NB;                           // NB+1
    int*      bcursor  = bbase + NB + 1;                      // NB

    k_cvt<<<2048, 256, 0, stream>>>(feat, fbf);
    hipMemsetAsync(bcnt, 0, NB * sizeof(int), stream);
    k_bhist<<<(N_EDGES + 2047) / 2048, 256, 0, stream>>>(dst, bcnt);
    k_bscan<<<1, 512, 0, stream>>>(bcnt, bbase, bcursor);
    k_bscatter<<<(N_EDGES + SC_CHUNK - 1) / SC_CHUNK, 256, 0, stream>>>(
        src, dst, etypes, bcursor, sorted_c);
    k_fine<<<NB, BN, 0, stream>>>(sorted_c, bbase, offsets, sorted_f);
    k_gather_post<<<GP_GRID, 256, 0, stream>>>(offsets, sorted_f, w_comp, feat,
                                               (const unsigned short*)fbf,
                                               weight, loop_weight, h_bias, out);
}